// Round 8
// baseline (11.331 us; speedup 1.0000x reference)
//
#include <hip/hip_runtime.h>
#include <math.h>

#define NH 32   // modes (N/2)

typedef _Float16 f16;
typedef _Float16 f16x2 __attribute__((ext_vector_type(2)));
typedef _Float16 f16x4 __attribute__((ext_vector_type(4)));
typedef float    f32x4 __attribute__((ext_vector_type(4)));

// Reduce x mod 2*pi to [-pi, pi], 2-term float Cody-Waite.
// PI2_HI = 6.28125 (8-bit mantissa) -> k*PI2_HI exact for k < 2^16.
__device__ __forceinline__ float reduce2pi(float x) {
    const float INV2PI = 0.15915494309189535f;
    const float PI2_HI = 6.28125f;
    const float PI2_LO = 1.9353071795864769e-3f;
    float k = rintf(x * INV2PI);
    float r = fmaf(-k, PI2_HI, x);
    r = fmaf(-k, PI2_LO, r);
    return r;
}

// Vandermonde-factored S4D: l = 128a + b (a<32, b<128)
//   K[h,l] = sum_n Re(G[n,a] * W[n,b]),  G = c_eff*u^a (u=z^128), W = z^b
// Computed as D[b][a] = sum_k X[b][k] * Y[k][a] with the k axis interleaved
// complex: k=2n -> (Wr, Gr), k=2n+1 -> (Wi, -Gi). Operand order (W as the
// M-side, G as the N-side) puts 4 CONSECUTIVE b in each lane's acc regs,
// and since l = 128a + b those are 4 consecutive output floats ->
// global_store_dwordx4, no staging. Fragment mapping validated by R7
// (absmax at f16-rounding level).
// Phase A is spread over 128 threads: thread (n, j) computes one of
// {z, z^128, z^1024, z^2048} (exact power-of-2 angle scalings).
__global__ __launch_bounds__(256, 4) void s4d_kernel(
    const float* __restrict__ log_dt,
    const float* __restrict__ Cv,          // (H, 32, 2)
    const float* __restrict__ log_A_real,  // (H, 32)
    const float* __restrict__ A_imag,      // (H, 32)
    float* __restrict__ Kout,              // (H, L), L = 4096
    int L)
{
    const int h   = blockIdx.x;
    const int tid = threadIdx.x;

    // pitch 68 f16 (136 B): 8B-aligned rows for f16x4 reads, 4B-aligned
    // packed writes, and enough skew to keep fragment reads ~2-way.
    __shared__ f16 Alds[32][68];     // Y: [a][k]  k=2n -> Gr, k=2n+1 -> -Gi
    __shared__ f16 Wlds[128][68];    // X: [b][k]  k=2n -> Wr, k=2n+1 -> Wi
    __shared__ float s_dar[NH], s_dai[NH];
    __shared__ float s_zr[NH],  s_zi[NH];    // z = exp(dtA)
    __shared__ float s_ur[NH],  s_ui[NH];    // u = z^128
    __shared__ float s_cer[NH], s_cei[NH];   // c_eff (x2 folded)
    __shared__ float s_e1r[NH], s_e1i[NH];   // z^1024
    __shared__ float s_e2r[NH], s_e2i[NH];   // z^2048

    // ---- Phase A: 128 threads; thread (n, j) does ONE exp+sincos chain ----
    if (tid < 128) {
        const int n = tid & 31;
        const int j = tid >> 5;              // 0:z(+c_eff) 1:u 2:e1 3:e2
        const float dt  = __expf(log_dt[h]);
        const float Ar  = -__expf(log_A_real[h * NH + n]);
        const float Ai  = A_imag[h * NH + n];
        const float dar = Ar * dt;
        const float dai = Ai * dt;
        const float S = (j == 0) ? 1.0f : (j == 1) ? 128.0f
                      : (j == 2) ? 1024.0f : 2048.0f;   // all exact scalings
        float e = __expf(dar * S);           // may underflow to 0: mode dead
        float sn, cs;
        __sincosf(reduce2pi(dai * S), &sn, &cs);
        float vr = e * cs, vi = e * sn;
        if (j == 0) {
            s_dar[n] = dar;  s_dai[n] = dai;
            s_zr[n] = vr;    s_zi[n] = vi;
            // c_eff = 2 * C * (z - 1)/A
            float edr = vr - 1.0f, edi = vi;
            float inv = 1.0f / fmaf(Ar, Ar, Ai * Ai);
            float fr  = (edr * Ar + edi * Ai) * inv;
            float fi  = (edi * Ar - edr * Ai) * inv;
            float cr  = Cv[(h * NH + n) * 2 + 0];
            float ci  = Cv[(h * NH + n) * 2 + 1];
            s_cer[n] = 2.0f * (cr * fr - ci * fi);
            s_cei[n] = 2.0f * (cr * fi + ci * fr);
        } else if (j == 1) { s_ur[n]  = vr;  s_ui[n]  = vi; }
        else if   (j == 2) { s_e1r[n] = vr;  s_e1i[n] = vi; }
        else               { s_e2r[n] = vr;  s_e2i[n] = vi; }
    }
    __syncthreads();

    const int lane = tid & 63;
    const int wv   = tid >> 6;       // wave id 0..3

    // ---- G build: wave wv fills rows a = 8wv..8wv+7 (lanes 0..31) ----
    if (lane < NH) {
        const int n = lane;
        float sr, si;                // seed = u^(8wv) from exact components
        if      (wv == 0) { sr = 1.0f;      si = 0.0f; }
        else if (wv == 1) { sr = s_e1r[n];  si = s_e1i[n]; }
        else if (wv == 2) { sr = s_e2r[n];  si = s_e2i[n]; }
        else {
            sr = s_e2r[n] * s_e1r[n] - s_e2i[n] * s_e1i[n];
            si = s_e2r[n] * s_e1i[n] + s_e2i[n] * s_e1r[n];
        }
        float gr = s_cer[n] * sr - s_cei[n] * si;
        float gi = s_cer[n] * si + s_cei[n] * sr;
        const float ur = s_ur[n], ui = s_ui[n];
        #pragma unroll
        for (int s = 0; s < 8; ++s) {
            const int a = wv * 8 + s;
            f16x2 pg = { (f16)gr, (f16)(-gi) };
            *reinterpret_cast<f16x2*>(&Alds[a][2 * n]) = pg;
            float t = gr * ur - gi * ui;     // g *= u
            gi = gr * ui + gi * ur;
            gr = t;
        }
    }

    // ---- W build: thread = (mode n, 16 consecutive b) ----
    {
        const int n  = tid & 31;
        const int bg = tid >> 5;                 // 0..7
        const float b0f = (float)(bg * 16);
        float e0 = __expf(s_dar[n] * b0f);
        float sn, cs;
        __sincosf(s_dai[n] * b0f, &sn, &cs);     // |ang| <= ~1100 rad (R2-R7)
        float wr = e0 * cs, wi = e0 * sn;        // W(n, b0)
        const float zr = s_zr[n], zi = s_zi[n];
        #pragma unroll
        for (int i = 0; i < 16; ++i) {
            const int b = bg * 16 + i;
            f16x2 pw = { (f16)wr, (f16)wi };
            *reinterpret_cast<f16x2*>(&Wlds[b][2 * n]) = pw;
            float t = wr * zr - wi * zi;         // w *= z
            wi = wr * zi + wi * zr;
            wr = t;
        }
    }
    __syncthreads();

    // ---- MFMA + direct vectorized store ----
    // X-frag: lane holds X[b = 32wv+16mi + (l&15)][k = 16ks + 4(l>>4) + j]
    // Y-frag: lane holds Y[k = 16ks + 4(l>>4) + j][a = 16ni + (l&15)]
    // D:      lane holds D[b = 32wv+16mi + 4(l>>4)+reg][a = 16ni + (l&15)]
    // l_out = 128a + b -> the 4 acc regs are 4 consecutive floats.
    const int r = lane & 15;
    const int q = lane >> 4;
    float* outp = Kout + (size_t)h * (size_t)L;
    #pragma unroll
    for (int mi = 0; mi < 2; ++mi) {
        #pragma unroll
        for (int ni = 0; ni < 2; ++ni) {
            f32x4 acc = {0.f, 0.f, 0.f, 0.f};
            #pragma unroll
            for (int ks = 0; ks < 4; ++ks) {
                f16x4 xf = *(const f16x4*)&Wlds[32 * wv + 16 * mi + r][16 * ks + 4 * q];
                f16x4 yf = *(const f16x4*)&Alds[16 * ni + r][16 * ks + 4 * q];
                acc = __builtin_amdgcn_mfma_f32_16x16x16f16(xf, yf, acc, 0, 0, 0);
            }
            const int a  = 16 * ni + r;
            const int b0 = 32 * wv + 16 * mi + 4 * q;
            *(f32x4*)&outp[(size_t)a * 128 + b0] = acc;
        }
    }
}

extern "C" void kernel_launch(void* const* d_in, const int* in_sizes, int n_in,
                              void* d_out, int out_size, void* d_ws, size_t ws_size,
                              hipStream_t stream) {
    // inputs: [0]=L (int scalar), [1]=log_dt (H,), [2]=C (H,32,2),
    //         [3]=log_A_real (H,32), [4]=A_imag (H,32)
    const float* log_dt     = (const float*)d_in[1];
    const float* Cv         = (const float*)d_in[2];
    const float* log_A_real = (const float*)d_in[3];
    const float* A_imag     = (const float*)d_in[4];
    float* Kout = (float*)d_out;

    const int Hn = in_sizes[1];          // 1024
    const int L  = out_size / Hn;        // 4096 (tiling assumes this)

    dim3 grid(Hn), block(256);
    hipLaunchKernelGGL(s4d_kernel, grid, block, 0, stream,
                       log_dt, Cv, log_A_real, A_imag, Kout, L);
}